// Round 3
// baseline (767.191 us; speedup 1.0000x reference)
//
#include <hip/hip_runtime.h>

#define B_ 4096
#define F_ 26
#define L_ 10
#define V_ 100000
#define D_ 128

// C[M,N] = act(A[M,K] @ W[K,N] + bias[N]); N, M multiples of 64.
template<bool RELU>
__global__ __launch_bounds__(256) void gemm_bias(
    const float* __restrict__ A, const float* __restrict__ W,
    const float* __restrict__ bias, float* __restrict__ C,
    int M, int N, int K)
{
    __shared__ __align__(16) float As[16][64];
    __shared__ __align__(16) float Bs[16][64];
    const int t  = threadIdx.x;
    const int tx = t & 15, ty = t >> 4;
    const int n0 = blockIdx.x * 64;
    const int m0 = blockIdx.y * 64;

    float acc[4][4] = {};

    for (int k0 = 0; k0 < K; k0 += 16) {
        #pragma unroll
        for (int i = 0; i < 4; ++i) {
            int e = t + i * 256;
            int m = e >> 4, k = e & 15;
            As[k][m] = (k0 + k < K) ? A[(size_t)(m0 + m) * K + k0 + k] : 0.f;
        }
        #pragma unroll
        for (int i = 0; i < 4; ++i) {
            int e = t + i * 256;
            int k = e >> 6, n = e & 63;
            Bs[k][n] = (k0 + k < K) ? W[(size_t)(k0 + k) * N + n0 + n] : 0.f;
        }
        __syncthreads();
        #pragma unroll
        for (int k = 0; k < 16; ++k) {
            float4 a = *reinterpret_cast<const float4*>(&As[k][ty * 4]);
            float4 b = *reinterpret_cast<const float4*>(&Bs[k][tx * 4]);
            float av[4] = {a.x, a.y, a.z, a.w};
            float bv[4] = {b.x, b.y, b.z, b.w};
            #pragma unroll
            for (int i = 0; i < 4; ++i)
                #pragma unroll
                for (int j = 0; j < 4; ++j)
                    acc[i][j] += av[i] * bv[j];
        }
        __syncthreads();
    }

    #pragma unroll
    for (int i = 0; i < 4; ++i) {
        int m = m0 + ty * 4 + i;
        #pragma unroll
        for (int j = 0; j < 4; ++j) {
            int n = n0 + tx * 4 + j;
            float v = acc[i][j] + bias[n];
            if (RELU) v = fmaxf(v, 0.f);
            C[(size_t)m * N + n] = v;
        }
    }
}

// One block per sample. Detects int32 vs int64 indices via odd-word scan
// (int64 values < 2^32 have zero high words; int32 random data can't have
// 128 consecutive zero odd words). Indices clamped: bad idx => wrong value
// (visible absmax), never a memory fault.
__global__ __launch_bounds__(256) void gather_interact(
    const float* __restrict__ emb_dense,   // [B,128]
    const int*   __restrict__ idx_words,   // indices buffer as 32-bit words
    const float* __restrict__ tables,      // [26,100000,128]
    float*       __restrict__ feats)       // [B,479]
{
    __shared__ __align__(16) float z[27][128];
    __shared__ int sidx[F_ * L_];
    __shared__ int sstride;
    const int b = blockIdx.x;
    const int t = threadIdx.x;

    if (t == 0) {
        int st = 2;  // assume int64 (odd words all zero)
        for (int w = 1; w < 256; w += 2)
            if (idx_words[w] != 0) { st = 1; break; }
        sstride = st;
    }
    __syncthreads();
    const int st = sstride;

    // FIX: F_*L_ = 260 > 256 threads — must stride, and clamp to [0, V).
    for (int s = t; s < F_ * L_; s += 256) {
        int v = idx_words[((size_t)b * F_ * L_ + s) * st];
        sidx[s] = v < 0 ? 0 : (v >= V_ ? V_ - 1 : v);
    }
    if (t < 128) {
        float v = emb_dense[(size_t)b * 128 + t];
        z[0][t] = v;
        feats[(size_t)b * 479 + t] = v;
    }
    __syncthreads();

    for (int s = t; s < F_ * 128; s += 256) {
        int f = s >> 7, d = s & 127;
        const float* tab = tables + (size_t)f * V_ * D_;
        float acc = 0.f;
        #pragma unroll
        for (int l = 0; l < L_; ++l) {
            int idx = sidx[f * L_ + l];
            acc += tab[(size_t)idx * D_ + d];
        }
        z[f + 1][d] = acc;
    }
    __syncthreads();

    for (int p = t; p < 351; p += 256) {
        int i = 0, rem = p;
        while (rem >= 26 - i) { rem -= 26 - i; ++i; }
        int j = i + 1 + rem;
        float dot = 0.f;
        for (int kk = 0; kk < 128; ++kk) {
            int k = (kk + t) & 127;
            dot += z[i][k] * z[j][k];
        }
        feats[(size_t)b * 479 + 128 + p] = dot;
    }
}

// logits[b] = dot(y[b,:256], w) + bias; one wave per row
__global__ __launch_bounds__(256) void final_dot(
    const float* __restrict__ y,    // [B,256]
    const float* __restrict__ w,    // [256]
    const float* __restrict__ bias, // [1]
    float*       __restrict__ out)  // [B]
{
    const int wave = threadIdx.x >> 6;
    const int lane = threadIdx.x & 63;
    const int b = blockIdx.x * 4 + wave;
    float4 yv = *reinterpret_cast<const float4*>(&y[(size_t)b * 256 + lane * 4]);
    float4 wv = *reinterpret_cast<const float4*>(&w[lane * 4]);
    float s = yv.x * wv.x + yv.y * wv.y + yv.z * wv.z + yv.w * wv.w;
    #pragma unroll
    for (int off = 32; off; off >>= 1) s += __shfl_xor(s, off);
    if (lane == 0) out[b] = s + bias[0];
}

extern "C" void kernel_launch(void* const* d_in, const int* in_sizes, int n_in,
                              void* d_out, int out_size, void* d_ws, size_t ws_size,
                              hipStream_t stream)
{
    const float* dense   = (const float*)d_in[0];
    const int*   indices = (const int*)  d_in[1];
    const float* tables  = (const float*)d_in[2];
    const float* dW0 = (const float*)d_in[3];  const float* db0 = (const float*)d_in[4];
    const float* dW1 = (const float*)d_in[5];  const float* db1 = (const float*)d_in[6];
    const float* dW2 = (const float*)d_in[7];  const float* db2 = (const float*)d_in[8];
    const float* oW0 = (const float*)d_in[9];  const float* ob0 = (const float*)d_in[10];
    const float* oW1 = (const float*)d_in[11]; const float* ob1 = (const float*)d_in[12];
    const float* oW2 = (const float*)d_in[13]; const float* ob2 = (const float*)d_in[14];
    const float* oW3 = (const float*)d_in[15]; const float* ob3 = (const float*)d_in[16];
    const float* oW4 = (const float*)d_in[17]; const float* ob4 = (const float*)d_in[18];
    float* out = (float*)d_out;

    // Single-pass layout with liveness-based reuse; high-water 39.3 MB
    // (round 0 wrote 48.2 MB to d_ws without fault, so this fits).
    float* ws = (float*)d_ws;
    float* x0    = ws;               // [B,512]  @ 0        .. 2,097,152
    float* x1    = ws + 2097152;     // [B,256]  ..3,145,728
    float* x2    = ws + 3145728;     // [B,128]  ..3,670,016
    float* feats = ws + 3670016;     // [B,479]  ..5,632,000   (x0,x1 dead)
    float* y0    = ws + 5632000;     // [B,1024] ..9,826,304
    float* y1    = ws;               // [B,1024] ..4,194,304   (x*,feats dead)
    float* y2    = ws + 5632000;     // [B,512]  ..7,729,152   (y0 dead)
    float* y3    = ws;               // [B,256]  ..1,048,576   (y1 dead)

    // bottom MLP
    gemm_bias<true><<<dim3(512 / 64, B_ / 64), 256, 0, stream>>>(dense, dW0, db0, x0, B_, 512, 13);
    gemm_bias<true><<<dim3(256 / 64, B_ / 64), 256, 0, stream>>>(x0,    dW1, db1, x1, B_, 256, 512);
    gemm_bias<true><<<dim3(128 / 64, B_ / 64), 256, 0, stream>>>(x1,    dW2, db2, x2, B_, 128, 256);

    // embedding gather + interaction + concat
    gather_interact<<<B_, 256, 0, stream>>>(x2, indices, tables, feats);

    // over MLP
    gemm_bias<true><<<dim3(1024 / 64, B_ / 64), 256, 0, stream>>>(feats, oW0, ob0, y0, B_, 1024, 479);
    gemm_bias<true><<<dim3(1024 / 64, B_ / 64), 256, 0, stream>>>(y0,    oW1, ob1, y1, B_, 1024, 1024);
    gemm_bias<true><<<dim3(512  / 64, B_ / 64), 256, 0, stream>>>(y1,    oW2, ob2, y2, B_, 512, 1024);
    gemm_bias<true><<<dim3(256  / 64, B_ / 64), 256, 0, stream>>>(y2,    oW3, ob3, y3, B_, 256, 512);

    final_dot<<<B_ / 4, 256, 0, stream>>>(y3, oW4, ob4, out);
}

// Round 4
// 715.035 us; speedup vs baseline: 1.0729x; 1.0729x over previous
//
#include <hip/hip_runtime.h>

#define B_ 4096
#define F_ 26
#define L_ 10
#define V_ 100000
#define D_ 128

typedef __attribute__((ext_vector_type(8))) short short8;
typedef __attribute__((ext_vector_type(4))) float f32x4;

#define LDK 40  // padded LDS row length in ushorts (80 B: 16B-aligned rows, banks spread)

// Split fp32 into hi+lo bf16 (both round-to-nearest-even). a ~= hi + lo,
// dropped residual ~2^-18 relative.
__device__ inline void split_bf16(float f, ushort& hi, ushort& lo) {
    union { float f; unsigned u; } a; a.f = f;
    unsigned r = (a.u + 0x7FFFu + ((a.u >> 16) & 1u)) >> 16;
    hi = (ushort)r;
    union { unsigned u; float f; } hf; hf.u = r << 16;
    float rem = f - hf.f;
    union { float f; unsigned u; } b; b.f = rem;
    unsigned r2 = (b.u + 0x7FFFu + ((b.u >> 16) & 1u)) >> 16;
    lo = (ushort)r2;
}

// C[M,N] = act(A[M,K] @ W[K,N] + bias[N]) via bf16x3 MFMA emulation of fp32.
// M, N multiples of 128. Tile 128x128, BK=32, 4 waves (each 64x64 out).
template<bool RELU>
__global__ __launch_bounds__(256) void gemm_mfma(
    const float* __restrict__ A, const float* __restrict__ W,
    const float* __restrict__ bias, float* __restrict__ C,
    int M, int N, int K)
{
    __shared__ ushort Ah[128 * LDK], Al[128 * LDK];
    __shared__ ushort Bh[128 * LDK], Bl[128 * LDK];   // B^T layout: [n][k]

    const int t    = threadIdx.x;
    const int lane = t & 63;
    const int w    = t >> 6;
    const int wm   = w >> 1, wn = w & 1;
    const int m0   = blockIdx.y * 128, n0 = blockIdx.x * 128;

    f32x4 acc[4][4];
    const f32x4 zero = {0.f, 0.f, 0.f, 0.f};
    #pragma unroll
    for (int i = 0; i < 4; ++i)
        #pragma unroll
        for (int j = 0; j < 4; ++j) acc[i][j] = zero;

    const bool kvec = ((K & 3) == 0);

    for (int k0 = 0; k0 < K; k0 += 32) {
        // ---- stage A tile: 128 rows x 32 k (fp32 -> hi/lo bf16) ----
        #pragma unroll
        for (int i = 0; i < 4; ++i) {
            int g   = t + (i << 8);          // 0..1023 float4 slots
            int row = g >> 3, k4 = g & 7;
            int kk  = k0 + (k4 << 2);
            const float* src = A + (size_t)(m0 + row) * K + kk;
            float4 v;
            if (kvec && kk + 4 <= K) {
                v = *reinterpret_cast<const float4*>(src);
            } else {
                v.x = (kk     < K) ? src[0] : 0.f;
                v.y = (kk + 1 < K) ? src[1] : 0.f;
                v.z = (kk + 2 < K) ? src[2] : 0.f;
                v.w = (kk + 3 < K) ? src[3] : 0.f;
            }
            ushort h0,h1,h2,h3,l0,l1,l2,l3;
            split_bf16(v.x, h0, l0); split_bf16(v.y, h1, l1);
            split_bf16(v.z, h2, l2); split_bf16(v.w, h3, l3);
            ushort4 hv = {h0,h1,h2,h3}, lv = {l0,l1,l2,l3};
            *reinterpret_cast<ushort4*>(&Ah[row * LDK + (k4 << 2)]) = hv;
            *reinterpret_cast<ushort4*>(&Al[row * LDK + (k4 << 2)]) = lv;
        }
        // ---- stage B tile transposed: W[k0..k0+32)[n0..n0+128) -> Bh/Bl[n][k] ----
        #pragma unroll
        for (int i = 0; i < 4; ++i) {
            int g  = t + (i << 8);           // 0..1023
            int n4 = g & 31, kk = g >> 5;    // kk 0..31
            float4 v = {0.f, 0.f, 0.f, 0.f};
            if (k0 + kk < K)
                v = *reinterpret_cast<const float4*>(W + (size_t)(k0 + kk) * N + n0 + (n4 << 2));
            float vv[4] = {v.x, v.y, v.z, v.w};
            #pragma unroll
            for (int j = 0; j < 4; ++j) {
                ushort h, l;
                split_bf16(vv[j], h, l);
                Bh[((n4 << 2) + j) * LDK + kk] = h;
                Bl[((n4 << 2) + j) * LDK + kk] = l;
            }
        }
        __syncthreads();

        // ---- fragments + 3-term MFMA ----
        const int kg = (lane >> 4) << 3;     // 0,8,16,24
        const int rr = lane & 15;
        short8 ah[4], al[4], bh[4], bl[4];
        #pragma unroll
        for (int ti = 0; ti < 4; ++ti) {
            int row = wm * 64 + ti * 16 + rr;
            ah[ti] = *reinterpret_cast<const short8*>(&Ah[row * LDK + kg]);
            al[ti] = *reinterpret_cast<const short8*>(&Al[row * LDK + kg]);
            int col = wn * 64 + ti * 16 + rr;
            bh[ti] = *reinterpret_cast<const short8*>(&Bh[col * LDK + kg]);
            bl[ti] = *reinterpret_cast<const short8*>(&Bl[col * LDK + kg]);
        }
        #pragma unroll
        for (int ti = 0; ti < 4; ++ti)
            #pragma unroll
            for (int tj = 0; tj < 4; ++tj) {
                f32x4 c = acc[ti][tj];
                c = __builtin_amdgcn_mfma_f32_16x16x32_bf16(ah[ti], bh[tj], c, 0, 0, 0);
                c = __builtin_amdgcn_mfma_f32_16x16x32_bf16(ah[ti], bl[tj], c, 0, 0, 0);
                c = __builtin_amdgcn_mfma_f32_16x16x32_bf16(al[ti], bh[tj], c, 0, 0, 0);
                acc[ti][tj] = c;
            }
        __syncthreads();
    }

    // ---- epilogue: C/D layout col=lane&15, row=(lane>>4)*4+r ----
    #pragma unroll
    for (int ti = 0; ti < 4; ++ti) {
        int row = m0 + wm * 64 + ti * 16 + ((lane >> 4) << 2);
        #pragma unroll
        for (int tj = 0; tj < 4; ++tj) {
            int col = n0 + wn * 64 + tj * 16 + (lane & 15);
            float bv = bias[col];
            #pragma unroll
            for (int r = 0; r < 4; ++r) {
                float v = acc[ti][tj][r] + bv;
                if (RELU) v = fmaxf(v, 0.f);
                C[(size_t)(row + r) * N + col] = v;
            }
        }
    }
}

// One block per sample. int32/int64 index probe + clamp (fault-proof).
__global__ __launch_bounds__(256) void gather_interact(
    const float* __restrict__ emb_dense,   // [B,128]
    const int*   __restrict__ idx_words,   // indices as 32-bit words
    const float* __restrict__ tables,      // [26,100000,128]
    float*       __restrict__ feats)       // [B,479]
{
    __shared__ __align__(16) float z[27][128];
    __shared__ int sidx[F_ * L_];
    __shared__ int sstride;
    const int b = blockIdx.x;
    const int t = threadIdx.x;

    if (t == 0) {
        int st = 2;  // int64: odd (high) words all zero
        for (int ww = 1; ww < 256; ww += 2)
            if (idx_words[ww] != 0) { st = 1; break; }
        sstride = st;
    }
    __syncthreads();
    const int st = sstride;

    for (int s = t; s < F_ * L_; s += 256) {
        int v = idx_words[((size_t)b * F_ * L_ + s) * st];
        sidx[s] = v < 0 ? 0 : (v >= V_ ? V_ - 1 : v);
    }
    if (t < 128) {
        float v = emb_dense[(size_t)b * 128 + t];
        z[0][t] = v;
        feats[(size_t)b * 479 + t] = v;
    }
    __syncthreads();

    for (int s = t; s < F_ * 128; s += 256) {
        int f = s >> 7, d = s & 127;
        const float* tab = tables + (size_t)f * V_ * D_;
        float acc = 0.f;
        #pragma unroll
        for (int l = 0; l < L_; ++l) {
            int idx = sidx[f * L_ + l];
            acc += tab[(size_t)idx * D_ + d];
        }
        z[f + 1][d] = acc;
    }
    __syncthreads();

    for (int p = t; p < 351; p += 256) {
        int i = 0, rem = p;
        while (rem >= 26 - i) { rem -= 26 - i; ++i; }
        int j = i + 1 + rem;
        float dot = 0.f;
        for (int kk = 0; kk < 128; ++kk) {
            int k = (kk + t) & 127;
            dot += z[i][k] * z[j][k];
        }
        feats[(size_t)b * 479 + 128 + p] = dot;
    }
}

// logits[b] = dot(y[b,:256], w) + bias; one wave per row
__global__ __launch_bounds__(256) void final_dot(
    const float* __restrict__ y, const float* __restrict__ w,
    const float* __restrict__ bias, float* __restrict__ out)
{
    const int wave = threadIdx.x >> 6;
    const int lane = threadIdx.x & 63;
    const int b = blockIdx.x * 4 + wave;
    float4 yv = *reinterpret_cast<const float4*>(&y[(size_t)b * 256 + lane * 4]);
    float4 wv = *reinterpret_cast<const float4*>(&w[lane * 4]);
    float s = yv.x * wv.x + yv.y * wv.y + yv.z * wv.z + yv.w * wv.w;
    #pragma unroll
    for (int off = 32; off; off >>= 1) s += __shfl_xor(s, off);
    if (lane == 0) out[b] = s + bias[0];
}

extern "C" void kernel_launch(void* const* d_in, const int* in_sizes, int n_in,
                              void* d_out, int out_size, void* d_ws, size_t ws_size,
                              hipStream_t stream)
{
    const float* dense   = (const float*)d_in[0];
    const int*   indices = (const int*)  d_in[1];
    const float* tables  = (const float*)d_in[2];
    const float* dW0 = (const float*)d_in[3];  const float* db0 = (const float*)d_in[4];
    const float* dW1 = (const float*)d_in[5];  const float* db1 = (const float*)d_in[6];
    const float* dW2 = (const float*)d_in[7];  const float* db2 = (const float*)d_in[8];
    const float* oW0 = (const float*)d_in[9];  const float* ob0 = (const float*)d_in[10];
    const float* oW1 = (const float*)d_in[11]; const float* ob1 = (const float*)d_in[12];
    const float* oW2 = (const float*)d_in[13]; const float* ob2 = (const float*)d_in[14];
    const float* oW3 = (const float*)d_in[15]; const float* ob3 = (const float*)d_in[16];
    const float* oW4 = (const float*)d_in[17]; const float* ob4 = (const float*)d_in[18];
    float* out = (float*)d_out;

    // Same proven layout as round 3; high-water 39.3 MB.
    float* ws = (float*)d_ws;
    float* x0    = ws;               // [B,512]
    float* x1    = ws + 2097152;     // [B,256]
    float* x2    = ws + 3145728;     // [B,128]
    float* feats = ws + 3670016;     // [B,479]
    float* y0    = ws + 5632000;     // [B,1024]
    float* y1    = ws;               // [B,1024]
    float* y2    = ws + 5632000;     // [B,512]
    float* y3    = ws;               // [B,256]

    gemm_mfma<true><<<dim3(512 / 128, B_ / 128), 256, 0, stream>>>(dense, dW0, db0, x0, B_, 512, 13);
    gemm_mfma<true><<<dim3(256 / 128, B_ / 128), 256, 0, stream>>>(x0,    dW1, db1, x1, B_, 256, 512);
    gemm_mfma<true><<<dim3(128 / 128, B_ / 128), 256, 0, stream>>>(x1,    dW2, db2, x2, B_, 128, 256);

    gather_interact<<<B_, 256, 0, stream>>>(x2, indices, tables, feats);

    gemm_mfma<true><<<dim3(1024 / 128, B_ / 128), 256, 0, stream>>>(feats, oW0, ob0, y0, B_, 1024, 479);
    gemm_mfma<true><<<dim3(1024 / 128, B_ / 128), 256, 0, stream>>>(y0,    oW1, ob1, y1, B_, 1024, 1024);
    gemm_mfma<true><<<dim3(512  / 128, B_ / 128), 256, 0, stream>>>(y1,    oW2, ob2, y2, B_, 512, 1024);
    gemm_mfma<true><<<dim3(256  / 128, B_ / 128), 256, 0, stream>>>(y2,    oW3, ob3, y3, B_, 256, 512);

    final_dot<<<B_ / 4, 256, 0, stream>>>(y3, oW4, ob4, out);
}

// Round 5
// 370.074 us; speedup vs baseline: 2.0731x; 1.9321x over previous
//
#include <hip/hip_runtime.h>

#define B_ 4096
#define F_ 26
#define L_ 10
#define V_ 100000
#define D_ 128

typedef __attribute__((ext_vector_type(8))) short short8;
typedef __attribute__((ext_vector_type(4))) float f32x4;

#define LDK 40  // padded LDS row length in ushorts (80 B rows)

// fp32 -> packed (hi_bf16 << 16) | lo_bf16, both RNE. value ~= hi + lo.
__device__ inline unsigned pack_split(float f) {
    union { float f; unsigned u; } a; a.f = f;
    unsigned r = (a.u + 0x7FFFu + ((a.u >> 16) & 1u)) >> 16;
    union { unsigned u; float f; } hf; hf.u = r << 16;
    float rem = f - hf.f;
    union { float f; unsigned u; } b; b.f = rem;
    unsigned r2 = (b.u + 0x7FFFu + ((b.u >> 16) & 1u)) >> 16;
    return (r << 16) | (r2 & 0xFFFFu);
}
__device__ inline float unpack_f(unsigned u) {
    union { unsigned u; float f; } h; h.u = u & 0xFFFF0000u;
    union { unsigned u; float f; } l; l.u = u << 16;
    return h.f + l.f;
}

// Transpose + split weights: W[K,N] fp32 -> Wt[N,Kp] packed uint, zero for k>=K.
__global__ __launch_bounds__(256) void prep_wt(
    const float* __restrict__ W, unsigned* __restrict__ Wt, int K, int N, int Kp)
{
    __shared__ float tile[32][33];
    const int t = threadIdx.x;
    const int tx = t & 31, ty = t >> 5;
    const int nb = blockIdx.x * 32, kb = blockIdx.y * 32;
    #pragma unroll
    for (int i = 0; i < 4; ++i) {
        int k = kb + ty + i * 8;
        tile[ty + i * 8][tx] = (k < K) ? W[(size_t)k * N + nb + tx] : 0.f;
    }
    __syncthreads();
    #pragma unroll
    for (int i = 0; i < 4; ++i) {
        int nl = ty + i * 8;
        Wt[(size_t)(nb + nl) * Kp + kb + tx] = pack_split(tile[tx][nl]);
    }
}

// dense [B,13] fp32 -> packed [B,32], zero-padded.
__global__ __launch_bounds__(256) void prep_dense(
    const float* __restrict__ dense, unsigned* __restrict__ out)
{
    int g = blockIdx.x * 256 + threadIdx.x;   // B*32 total
    int b = g >> 5, k = g & 31;
    out[g] = (k < 13) ? pack_split(dense[(size_t)b * 13 + k]) : 0u;
}

// C = act(A @ W + bias). A: packed [M,Kp]; Wt: packed [N,Kp]; C: packed [M,N].
// Kp multiple of 32, N multiple of 128 (or ==128), M multiple of 128.
template<bool RELU>
__global__ __launch_bounds__(256) void gemm_p(
    const unsigned* __restrict__ Ap, const unsigned* __restrict__ Wt,
    const float* __restrict__ bias, unsigned* __restrict__ Cp,
    int M, int N, int Kp)
{
    __shared__ ushort Ah[128 * LDK], Al[128 * LDK];
    __shared__ ushort Bh[128 * LDK], Bl[128 * LDK];

    const int t    = threadIdx.x;
    const int lane = t & 63;
    const int w    = t >> 6;
    const int wm   = w >> 1, wn = w & 1;
    const int m0   = blockIdx.y * 128, n0 = blockIdx.x * 128;

    f32x4 acc[4][4];
    const f32x4 zero = {0.f, 0.f, 0.f, 0.f};
    #pragma unroll
    for (int i = 0; i < 4; ++i)
        #pragma unroll
        for (int j = 0; j < 4; ++j) acc[i][j] = zero;

    const unsigned* Ab = Ap + (size_t)m0 * Kp;
    const unsigned* Bb = Wt + (size_t)n0 * Kp;

    for (int k0 = 0; k0 < Kp; k0 += 32) {
        // stage A and B tiles: straight packed copy, unpack hi/lo.
        #pragma unroll
        for (int i = 0; i < 4; ++i) {
            int g = t + (i << 8);            // 0..1023
            int row = g >> 3, k4 = g & 7;
            uint4 va = *reinterpret_cast<const uint4*>(Ab + (size_t)row * Kp + k0 + (k4 << 2));
            ushort4 hv = {(ushort)(va.x >> 16), (ushort)(va.y >> 16), (ushort)(va.z >> 16), (ushort)(va.w >> 16)};
            ushort4 lv = {(ushort)(va.x & 0xFFFF), (ushort)(va.y & 0xFFFF), (ushort)(va.z & 0xFFFF), (ushort)(va.w & 0xFFFF)};
            *reinterpret_cast<ushort4*>(&Ah[row * LDK + (k4 << 2)]) = hv;
            *reinterpret_cast<ushort4*>(&Al[row * LDK + (k4 << 2)]) = lv;
            uint4 vb = *reinterpret_cast<const uint4*>(Bb + (size_t)row * Kp + k0 + (k4 << 2));
            ushort4 hb = {(ushort)(vb.x >> 16), (ushort)(vb.y >> 16), (ushort)(vb.z >> 16), (ushort)(vb.w >> 16)};
            ushort4 lb = {(ushort)(vb.x & 0xFFFF), (ushort)(vb.y & 0xFFFF), (ushort)(vb.z & 0xFFFF), (ushort)(vb.w & 0xFFFF)};
            *reinterpret_cast<ushort4*>(&Bh[row * LDK + (k4 << 2)]) = hb;
            *reinterpret_cast<ushort4*>(&Bl[row * LDK + (k4 << 2)]) = lb;
        }
        __syncthreads();

        const int kg = (lane >> 4) << 3;
        const int rr = lane & 15;
        short8 bh[4], bl[4];
        #pragma unroll
        for (int tj = 0; tj < 4; ++tj) {
            int col = wn * 64 + tj * 16 + rr;
            bh[tj] = *reinterpret_cast<const short8*>(&Bh[col * LDK + kg]);
            bl[tj] = *reinterpret_cast<const short8*>(&Bl[col * LDK + kg]);
        }
        #pragma unroll
        for (int ti = 0; ti < 4; ++ti) {
            int row = wm * 64 + ti * 16 + rr;
            short8 ah = *reinterpret_cast<const short8*>(&Ah[row * LDK + kg]);
            short8 al = *reinterpret_cast<const short8*>(&Al[row * LDK + kg]);
            #pragma unroll
            for (int tj = 0; tj < 4; ++tj) {
                f32x4 c = acc[ti][tj];
                c = __builtin_amdgcn_mfma_f32_16x16x32_bf16(ah, bh[tj], c, 0, 0, 0);
                c = __builtin_amdgcn_mfma_f32_16x16x32_bf16(ah, bl[tj], c, 0, 0, 0);
                c = __builtin_amdgcn_mfma_f32_16x16x32_bf16(al, bh[tj], c, 0, 0, 0);
                acc[ti][tj] = c;
            }
        }
        __syncthreads();
    }

    #pragma unroll
    for (int ti = 0; ti < 4; ++ti) {
        int row = m0 + wm * 64 + ti * 16 + ((lane >> 4) << 2);
        #pragma unroll
        for (int tj = 0; tj < 4; ++tj) {
            int col = n0 + wn * 64 + tj * 16 + (lane & 15);
            float bv = bias[col];
            #pragma unroll
            for (int r = 0; r < 4; ++r) {
                float v = acc[ti][tj][r] + bv;
                if (RELU) v = fmaxf(v, 0.f);
                Cp[(size_t)(row + r) * N + col] = pack_split(v);
            }
        }
    }
}

// One block per sample: float4 gather into LDS z, pairwise dots, packed feats.
__global__ __launch_bounds__(256) void gather_interact(
    const unsigned* __restrict__ x2p,      // [B,128] packed
    const int*      __restrict__ idx_words,
    const float*    __restrict__ tables,   // [26,100000,128] fp32
    unsigned*       __restrict__ featsp)   // [B,480] packed
{
    __shared__ __align__(16) float z[27][132];
    __shared__ int sidx[F_ * L_];
    __shared__ int sstride;
    const int b = blockIdx.x;
    const int t = threadIdx.x;

    if (t == 0) {
        int st = 2;  // int64: odd (high) words all zero
        for (int ww = 1; ww < 256; ww += 2)
            if (idx_words[ww] != 0) { st = 1; break; }
        sstride = st;
        featsp[(size_t)b * 480 + 479] = 0u;
    }
    __syncthreads();
    const int st = sstride;

    for (int s = t; s < F_ * L_; s += 256) {
        int v = idx_words[((size_t)b * F_ * L_ + s) * st];
        sidx[s] = v < 0 ? 0 : (v >= V_ ? V_ - 1 : v);
    }
    if (t < 128) {
        unsigned u = x2p[(size_t)b * 128 + t];
        z[0][t] = unpack_f(u);
        featsp[(size_t)b * 480 + t] = u;
    }
    __syncthreads();

    // gather: 26 features x 32 float4-slots
    for (int s = t; s < F_ * 32; s += 256) {
        int f = s >> 5, d4 = s & 31;
        const float* tab = tables + (size_t)f * V_ * D_;
        float4 a4 = {0.f, 0.f, 0.f, 0.f};
        #pragma unroll
        for (int l = 0; l < L_; ++l) {
            int idx = sidx[f * L_ + l];
            float4 v = *reinterpret_cast<const float4*>(tab + (size_t)idx * D_ + (d4 << 2));
            a4.x += v.x; a4.y += v.y; a4.z += v.z; a4.w += v.w;
        }
        *reinterpret_cast<float4*>(&z[f + 1][d4 << 2]) = a4;
    }
    __syncthreads();

    for (int p = t; p < 351; p += 256) {
        int i = 0, rem = p;
        while (rem >= 26 - i) { rem -= 26 - i; ++i; }
        int j = i + 1 + rem;
        float4 s4 = {0.f, 0.f, 0.f, 0.f};
        for (int kk = 0; kk < 32; ++kk) {
            int k4 = (kk + t) & 31;
            float4 a = *reinterpret_cast<const float4*>(&z[i][k4 << 2]);
            float4 c = *reinterpret_cast<const float4*>(&z[j][k4 << 2]);
            s4.x += a.x * c.x; s4.y += a.y * c.y; s4.z += a.z * c.z; s4.w += a.w * c.w;
        }
        featsp[(size_t)b * 480 + 128 + p] = pack_split(s4.x + s4.y + s4.z + s4.w);
    }
}

// logits[b] = dot(unpack(y3p[b,:256]), w) + bias
__global__ __launch_bounds__(256) void final_dot(
    const unsigned* __restrict__ yp, const float* __restrict__ w,
    const float* __restrict__ bias, float* __restrict__ out)
{
    const int wave = threadIdx.x >> 6;
    const int lane = threadIdx.x & 63;
    const int b = blockIdx.x * 4 + wave;
    uint4 u = *reinterpret_cast<const uint4*>(yp + (size_t)b * 256 + lane * 4);
    float4 wv = *reinterpret_cast<const float4*>(&w[lane * 4]);
    float s = unpack_f(u.x) * wv.x + unpack_f(u.y) * wv.y +
              unpack_f(u.z) * wv.z + unpack_f(u.w) * wv.w;
    #pragma unroll
    for (int off = 32; off; off >>= 1) s += __shfl_xor(s, off);
    if (lane == 0) out[b] = s + bias[0];
}

extern "C" void kernel_launch(void* const* d_in, const int* in_sizes, int n_in,
                              void* d_out, int out_size, void* d_ws, size_t ws_size,
                              hipStream_t stream)
{
    const float* dense   = (const float*)d_in[0];
    const int*   indices = (const int*)  d_in[1];
    const float* tables  = (const float*)d_in[2];
    const float* dW0 = (const float*)d_in[3];  const float* db0 = (const float*)d_in[4];
    const float* dW1 = (const float*)d_in[5];  const float* db1 = (const float*)d_in[6];
    const float* dW2 = (const float*)d_in[7];  const float* db2 = (const float*)d_in[8];
    const float* oW0 = (const float*)d_in[9];  const float* ob0 = (const float*)d_in[10];
    const float* oW1 = (const float*)d_in[11]; const float* ob1 = (const float*)d_in[12];
    const float* oW2 = (const float*)d_in[13]; const float* ob2 = (const float*)d_in[14];
    const float* oW3 = (const float*)d_in[15]; const float* ob3 = (const float*)d_in[16];
    const float* oW4 = (const float*)d_in[17]; const float* ob4 = (const float*)d_in[18];
    float* out = (float*)d_out;

    unsigned* wsu = (unsigned*)d_ws;
    // packed weight (transposed) offsets, in uints
    unsigned* dWt0 = wsu + 0;          // [512][32]
    unsigned* dWt1 = wsu + 16384;      // [256][512]
    unsigned* dWt2 = wsu + 147456;     // [128][256]
    unsigned* oWt0 = wsu + 180224;     // [1024][480]
    unsigned* oWt1 = wsu + 671744;     // [1024][1024]
    unsigned* oWt2 = wsu + 1720320;    // [512][1024]
    unsigned* oWt3 = wsu + 2244608;    // [256][512]
    unsigned* densep = wsu + 2375680;  // [4096][32]
    unsigned* x2p    = wsu + 2506752;  // [4096][128]
    unsigned* featsp = wsu + 3031040;  // [4096][480]
    unsigned* x0p    = wsu + 5000000;  // [4096][512]
    unsigned* x1p    = wsu + 7097152;  // [4096][256]
    unsigned* y0p    = wsu + 5000000;  // [4096][1024] (x0p/x1p dead)
    unsigned* y1p    = wsu + 9194304;  // [4096][1024]
    unsigned* y2p    = wsu + 2506752;  // [4096][512]  (x2p/featsp dead)
    unsigned* y3p    = wsu + 5000000;  // [4096][256]  (y0p dead)
    // high water: 13,388,608 uints = 53.6 MB (d_ws poison shows 5.2 GB available)

    // --- prep: transpose+split weights, pad+split dense ---
    prep_wt<<<dim3(512 / 32,  32 / 32),   256, 0, stream>>>(dW0, dWt0, 13,   512,  32);
    prep_wt<<<dim3(256 / 32,  512 / 32),  256, 0, stream>>>(dW1, dWt1, 512,  256,  512);
    prep_wt<<<dim3(128 / 32,  256 / 32),  256, 0, stream>>>(dW2, dWt2, 256,  128,  256);
    prep_wt<<<dim3(1024 / 32, 480 / 32),  256, 0, stream>>>(oW0, oWt0, 479,  1024, 480);
    prep_wt<<<dim3(1024 / 32, 1024 / 32), 256, 0, stream>>>(oW1, oWt1, 1024, 1024, 1024);
    prep_wt<<<dim3(512 / 32,  1024 / 32), 256, 0, stream>>>(oW2, oWt2, 1024, 512,  1024);
    prep_wt<<<dim3(256 / 32,  512 / 32),  256, 0, stream>>>(oW3, oWt3, 512,  256,  512);
    prep_dense<<<(B_ * 32) / 256, 256, 0, stream>>>(dense, densep);

    // --- bottom MLP ---
    gemm_p<true><<<dim3(512 / 128, B_ / 128), 256, 0, stream>>>(densep, dWt0, db0, x0p, B_, 512, 32);
    gemm_p<true><<<dim3(256 / 128, B_ / 128), 256, 0, stream>>>(x0p,    dWt1, db1, x1p, B_, 256, 512);
    gemm_p<true><<<dim3(128 / 128, B_ / 128), 256, 0, stream>>>(x1p,    dWt2, db2, x2p, B_, 128, 256);

    // --- gather + interaction ---
    gather_interact<<<B_, 256, 0, stream>>>(x2p, indices, tables, featsp);

    // --- over MLP ---
    gemm_p<true><<<dim3(1024 / 128, B_ / 128), 256, 0, stream>>>(featsp, oWt0, ob0, y0p, B_, 1024, 480);
    gemm_p<true><<<dim3(1024 / 128, B_ / 128), 256, 0, stream>>>(y0p,    oWt1, ob1, y1p, B_, 1024, 1024);
    gemm_p<true><<<dim3(512  / 128, B_ / 128), 256, 0, stream>>>(y1p,    oWt2, ob2, y2p, B_, 512, 1024);
    gemm_p<true><<<dim3(256  / 128, B_ / 128), 256, 0, stream>>>(y2p,    oWt3, ob3, y3p, B_, 256, 512);

    final_dot<<<B_ / 4, 256, 0, stream>>>(y3p, oW4, ob4, out);
}

// Round 6
// 330.672 us; speedup vs baseline: 2.3201x; 1.1192x over previous
//
#include <hip/hip_runtime.h>

#define B_ 4096
#define F_ 26
#define L_ 10
#define V_ 100000
#define D_ 128

typedef __attribute__((ext_vector_type(8))) short short8;
typedef __attribute__((ext_vector_type(4))) float f32x4;

// fp32 -> packed (hi_bf16 << 16) | lo_bf16, both RNE. value ~= hi + lo.
__device__ inline unsigned pack_split(float f) {
    union { float f; unsigned u; } a; a.f = f;
    unsigned r = (a.u + 0x7FFFu + ((a.u >> 16) & 1u)) >> 16;
    union { unsigned u; float f; } hf; hf.u = r << 16;
    float rem = f - hf.f;
    union { float f; unsigned u; } b; b.f = rem;
    unsigned r2 = (b.u + 0x7FFFu + ((b.u >> 16) & 1u)) >> 16;
    return (r << 16) | (r2 & 0xFFFFu);
}
__device__ inline float unpack_f(unsigned u) {
    union { unsigned u; float f; } h; h.u = u & 0xFFFF0000u;
    union { unsigned u; float f; } l; l.u = u << 16;
    return h.f + l.f;
}

// ---- merged prep: 7 weight transposes + dense pad in ONE launch ----
__device__ void prep_tile(const float* __restrict__ W, unsigned* __restrict__ Wt,
                          int K, int N, int Kp, int local)
{
    __shared__ float tile[32][33];
    const int t = threadIdx.x;
    const int tx = t & 31, ty = t >> 5;
    const int nbt = N >> 5;
    const int nb = (local % nbt) << 5, kb = (local / nbt) << 5;
    #pragma unroll
    for (int i = 0; i < 4; ++i) {
        int k = kb + ty + i * 8;
        tile[ty + i * 8][tx] = (k < K) ? W[(size_t)k * N + nb + tx] : 0.f;
    }
    __syncthreads();
    #pragma unroll
    for (int i = 0; i < 4; ++i) {
        int nl = ty + i * 8;
        Wt[(size_t)(nb + nl) * Kp + kb + tx] = pack_split(tile[tx][nl]);
    }
}

__global__ __launch_bounds__(256) void prep_all(
    const float* dW0, const float* dW1, const float* dW2,
    const float* oW0, const float* oW1, const float* oW2, const float* oW3,
    unsigned* dWt0, unsigned* dWt1, unsigned* dWt2,
    unsigned* oWt0, unsigned* oWt1, unsigned* oWt2, unsigned* oWt3,
    const float* dense, unsigned* densep)
{
    const int bid = blockIdx.x;
    if      (bid < 16)   prep_tile(dW0, dWt0, 13,   512,  32,   bid);
    else if (bid < 144)  prep_tile(dW1, dWt1, 512,  256,  512,  bid - 16);
    else if (bid < 176)  prep_tile(dW2, dWt2, 256,  128,  256,  bid - 144);
    else if (bid < 656)  prep_tile(oW0, oWt0, 479,  1024, 480,  bid - 176);
    else if (bid < 1680) prep_tile(oW1, oWt1, 1024, 1024, 1024, bid - 656);
    else if (bid < 2192) prep_tile(oW2, oWt2, 1024, 512,  1024, bid - 1680);
    else if (bid < 2320) prep_tile(oW3, oWt3, 512,  256,  512,  bid - 2320 + 128);
    else {
        int g = (bid - 2320) * 256 + threadIdx.x;   // B*32 slots
        int b = g >> 5, k = g & 31;
        densep[g] = (k < 13) ? pack_split(dense[(size_t)b * 13 + k]) : 0u;
    }
}

// C = act(A @ W + bias), bf16x3 MFMA. A:[M,Kp] packed, Wt:[N,Kp] packed,
// C:[M,N] packed. Tile 128x128, BK=32 uints. LDS linear packed tiles staged
// via global_load_lds (16B) with source-side chunk swizzle ch^(row&7);
// fragment reads use the same swizzle -> conflict-free b128.
template<bool RELU>
__global__ __launch_bounds__(256) void gemm_p2(
    const unsigned* __restrict__ Ap, const unsigned* __restrict__ Wt,
    const float* __restrict__ bias, unsigned* __restrict__ Cp,
    int M, int N, int Kp)
{
    __shared__ __align__(16) unsigned Au[128 * 32];
    __shared__ __align__(16) unsigned Bu[128 * 32];

    const int t    = threadIdx.x;
    const int lane = t & 63;
    const int w    = t >> 6;
    const int wm   = w >> 1, wn = w & 1;
    const int m0   = blockIdx.y * 128, n0 = blockIdx.x * 128;

    f32x4 acc[4][4];
    const f32x4 zero = {0.f, 0.f, 0.f, 0.f};
    #pragma unroll
    for (int i = 0; i < 4; ++i)
        #pragma unroll
        for (int j = 0; j < 4; ++j) acc[i][j] = zero;

    const unsigned* Ab = Ap + (size_t)m0 * Kp;
    const unsigned* Bb = Wt + (size_t)n0 * Kp;

    const int g4 = lane >> 4;        // k-group 0..3
    const int rr = lane & 15;

    for (int k0 = 0; k0 < Kp; k0 += 32) {
        #pragma unroll
        for (int i = 0; i < 4; ++i) {
            int chunk = t + (i << 8);            // 0..1023 16B chunks
            int row = chunk >> 3, ch = chunk & 7;
            int sch = ch ^ (row & 7);            // source-side swizzle
            __builtin_amdgcn_global_load_lds(
                (const __attribute__((address_space(1))) unsigned*)(Ab + (size_t)row * Kp + k0 + (sch << 2)),
                &Au[chunk << 2], 16, 0, 0);
            __builtin_amdgcn_global_load_lds(
                (const __attribute__((address_space(1))) unsigned*)(Bb + (size_t)row * Kp + k0 + (sch << 2)),
                &Bu[chunk << 2], 16, 0, 0);
        }
        __syncthreads();

        // B fragments (kept in regs across ti loop)
        short8 bh[4], bl[4];
        #pragma unroll
        for (int tj = 0; tj < 4; ++tj) {
            int r = wn * 64 + tj * 16 + rr;
            int c0 = (2 * g4) ^ (r & 7), c1 = (2 * g4 + 1) ^ (r & 7);
            uint4 p = *reinterpret_cast<const uint4*>(&Bu[r * 32 + (c0 << 2)]);
            uint4 q = *reinterpret_cast<const uint4*>(&Bu[r * 32 + (c1 << 2)]);
            union { short8 s; uint4 u; } H, L;
            H.u.x = __builtin_amdgcn_perm(p.y, p.x, 0x07060302u);
            L.u.x = __builtin_amdgcn_perm(p.y, p.x, 0x05040100u);
            H.u.y = __builtin_amdgcn_perm(p.w, p.z, 0x07060302u);
            L.u.y = __builtin_amdgcn_perm(p.w, p.z, 0x05040100u);
            H.u.z = __builtin_amdgcn_perm(q.y, q.x, 0x07060302u);
            L.u.z = __builtin_amdgcn_perm(q.y, q.x, 0x05040100u);
            H.u.w = __builtin_amdgcn_perm(q.w, q.z, 0x07060302u);
            L.u.w = __builtin_amdgcn_perm(q.w, q.z, 0x05040100u);
            bh[tj] = H.s; bl[tj] = L.s;
        }
        #pragma unroll
        for (int ti = 0; ti < 4; ++ti) {
            int r = wm * 64 + ti * 16 + rr;
            int c0 = (2 * g4) ^ (r & 7), c1 = (2 * g4 + 1) ^ (r & 7);
            uint4 p = *reinterpret_cast<const uint4*>(&Au[r * 32 + (c0 << 2)]);
            uint4 q = *reinterpret_cast<const uint4*>(&Au[r * 32 + (c1 << 2)]);
            union { short8 s; uint4 u; } H, L;
            H.u.x = __builtin_amdgcn_perm(p.y, p.x, 0x07060302u);
            L.u.x = __builtin_amdgcn_perm(p.y, p.x, 0x05040100u);
            H.u.y = __builtin_amdgcn_perm(p.w, p.z, 0x07060302u);
            L.u.y = __builtin_amdgcn_perm(p.w, p.z, 0x05040100u);
            H.u.z = __builtin_amdgcn_perm(q.y, q.x, 0x07060302u);
            L.u.z = __builtin_amdgcn_perm(q.y, q.x, 0x05040100u);
            H.u.w = __builtin_amdgcn_perm(q.w, q.z, 0x07060302u);
            L.u.w = __builtin_amdgcn_perm(q.w, q.z, 0x05040100u);
            short8 ah = H.s, al = L.s;
            #pragma unroll
            for (int tj = 0; tj < 4; ++tj) {
                f32x4 c = acc[ti][tj];
                c = __builtin_amdgcn_mfma_f32_16x16x32_bf16(ah, bh[tj], c, 0, 0, 0);
                c = __builtin_amdgcn_mfma_f32_16x16x32_bf16(ah, bl[tj], c, 0, 0, 0);
                c = __builtin_amdgcn_mfma_f32_16x16x32_bf16(al, bh[tj], c, 0, 0, 0);
                acc[ti][tj] = c;
            }
        }
        __syncthreads();
    }

    #pragma unroll
    for (int ti = 0; ti < 4; ++ti) {
        int row = m0 + wm * 64 + ti * 16 + ((lane >> 4) << 2);
        #pragma unroll
        for (int tj = 0; tj < 4; ++tj) {
            int col = n0 + wn * 64 + tj * 16 + (lane & 15);
            float bv = bias[col];
            #pragma unroll
            for (int r = 0; r < 4; ++r) {
                float v = acc[ti][tj][r] + bv;
                if (RELU) v = fmaxf(v, 0.f);
                Cp[(size_t)(row + r) * N + col] = pack_split(v);
            }
        }
    }
}

// One block per sample: float4 gather into LDS z, pairwise dots, packed feats.
__global__ __launch_bounds__(256) void gather_interact(
    const unsigned* __restrict__ x2p,      // [B,128] packed
    const int*      __restrict__ idx_words,
    const float*    __restrict__ tables,   // [26,100000,128] fp32
    unsigned*       __restrict__ featsp)   // [B,480] packed
{
    __shared__ __align__(16) float z[27][132];
    __shared__ int sidx[F_ * L_];
    __shared__ int sstride;
    const int b = blockIdx.x;
    const int t = threadIdx.x;

    if (t == 0) {
        int st = 2;  // int64: odd (high) words all zero
        for (int ww = 1; ww < 256; ww += 2)
            if (idx_words[ww] != 0) { st = 1; break; }
        sstride = st;
        featsp[(size_t)b * 480 + 479] = 0u;
    }
    __syncthreads();
    const int st = sstride;

    for (int s = t; s < F_ * L_; s += 256) {
        int v = idx_words[((size_t)b * F_ * L_ + s) * st];
        sidx[s] = v < 0 ? 0 : (v >= V_ ? V_ - 1 : v);
    }
    if (t < 128) {
        unsigned u = x2p[(size_t)b * 128 + t];
        z[0][t] = unpack_f(u);
        featsp[(size_t)b * 480 + t] = u;
    }
    __syncthreads();

    for (int s = t; s < F_ * 32; s += 256) {
        int f = s >> 5, d4 = s & 31;
        const float* tab = tables + (size_t)f * V_ * D_;
        float4 a4 = {0.f, 0.f, 0.f, 0.f};
        #pragma unroll
        for (int l = 0; l < L_; ++l) {
            int idx = sidx[f * L_ + l];
            float4 v = *reinterpret_cast<const float4*>(tab + (size_t)idx * D_ + (d4 << 2));
            a4.x += v.x; a4.y += v.y; a4.z += v.z; a4.w += v.w;
        }
        *reinterpret_cast<float4*>(&z[f + 1][d4 << 2]) = a4;
    }
    __syncthreads();

    for (int p = t; p < 351; p += 256) {
        int i = 0, rem = p;
        while (rem >= 26 - i) { rem -= 26 - i; ++i; }
        int j = i + 1 + rem;
        float4 s4 = {0.f, 0.f, 0.f, 0.f};
        for (int kk = 0; kk < 32; ++kk) {
            int k4 = (kk + t) & 31;
            float4 a = *reinterpret_cast<const float4*>(&z[i][k4 << 2]);
            float4 c = *reinterpret_cast<const float4*>(&z[j][k4 << 2]);
            s4.x += a.x * c.x; s4.y += a.y * c.y; s4.z += a.z * c.z; s4.w += a.w * c.w;
        }
        featsp[(size_t)b * 480 + 128 + p] = pack_split(s4.x + s4.y + s4.z + s4.w);
    }
}

// logits[b] = dot(unpack(y3p[b,:256]), w) + bias
__global__ __launch_bounds__(256) void final_dot(
    const unsigned* __restrict__ yp, const float* __restrict__ w,
    const float* __restrict__ bias, float* __restrict__ out)
{
    const int wave = threadIdx.x >> 6;
    const int lane = threadIdx.x & 63;
    const int b = blockIdx.x * 4 + wave;
    uint4 u = *reinterpret_cast<const uint4*>(yp + (size_t)b * 256 + lane * 4);
    float4 wv = *reinterpret_cast<const float4*>(&w[lane * 4]);
    float s = unpack_f(u.x) * wv.x + unpack_f(u.y) * wv.y +
              unpack_f(u.z) * wv.z + unpack_f(u.w) * wv.w;
    #pragma unroll
    for (int off = 32; off; off >>= 1) s += __shfl_xor(s, off);
    if (lane == 0) out[b] = s + bias[0];
}

extern "C" void kernel_launch(void* const* d_in, const int* in_sizes, int n_in,
                              void* d_out, int out_size, void* d_ws, size_t ws_size,
                              hipStream_t stream)
{
    const float* dense   = (const float*)d_in[0];
    const int*   indices = (const int*)  d_in[1];
    const float* tables  = (const float*)d_in[2];
    const float* dW0 = (const float*)d_in[3];  const float* db0 = (const float*)d_in[4];
    const float* dW1 = (const float*)d_in[5];  const float* db1 = (const float*)d_in[6];
    const float* dW2 = (const float*)d_in[7];  const float* db2 = (const float*)d_in[8];
    const float* oW0 = (const float*)d_in[9];  const float* ob0 = (const float*)d_in[10];
    const float* oW1 = (const float*)d_in[11]; const float* ob1 = (const float*)d_in[12];
    const float* oW2 = (const float*)d_in[13]; const float* ob2 = (const float*)d_in[14];
    const float* oW3 = (const float*)d_in[15]; const float* ob3 = (const float*)d_in[16];
    const float* oW4 = (const float*)d_in[17]; const float* ob4 = (const float*)d_in[18];
    float* out = (float*)d_out;

    unsigned* wsu = (unsigned*)d_ws;
    unsigned* dWt0 = wsu + 0;          // [512][32]
    unsigned* dWt1 = wsu + 16384;      // [256][512]
    unsigned* dWt2 = wsu + 147456;     // [128][256]
    unsigned* oWt0 = wsu + 180224;     // [1024][480]
    unsigned* oWt1 = wsu + 671744;     // [1024][1024]
    unsigned* oWt2 = wsu + 1720320;    // [512][1024]
    unsigned* oWt3 = wsu + 2244608;    // [256][512]
    unsigned* densep = wsu + 2375680;  // [4096][32]
    unsigned* x2p    = wsu + 2506752;  // [4096][128]
    unsigned* featsp = wsu + 3031040;  // [4096][480]
    unsigned* x0p    = wsu + 5000000;  // [4096][512]
    unsigned* x1p    = wsu + 7097152;  // [4096][256]
    unsigned* y0p    = wsu + 5000000;  // [4096][1024] (x0p/x1p dead)
    unsigned* y1p    = wsu + 9194304;  // [4096][1024]
    unsigned* y2p    = wsu + 2506752;  // [4096][512]  (x2p/featsp dead)
    unsigned* y3p    = wsu + 5000000;  // [4096][256]  (y0p dead)
    // high water 53.6 MB (d_ws poison fill shows 5.2 GB available)

    prep_all<<<2832, 256, 0, stream>>>(dW0, dW1, dW2, oW0, oW1, oW2, oW3,
                                       dWt0, dWt1, dWt2, oWt0, oWt1, oWt2, oWt3,
                                       dense, densep);

    gemm_p2<true><<<dim3(4, B_ / 128), 256, 0, stream>>>(densep, dWt0, db0, x0p, B_, 512, 32);
    gemm_p2<true><<<dim3(2, B_ / 128), 256, 0, stream>>>(x0p,    dWt1, db1, x1p, B_, 256, 512);
    gemm_p2<true><<<dim3(1, B_ / 128), 256, 0, stream>>>(x1p,    dWt2, db2, x2p, B_, 128, 256);

    gather_interact<<<B_, 256, 0, stream>>>(x2p, indices, tables, featsp);

    gemm_p2<true><<<dim3(8, B_ / 128), 256, 0, stream>>>(featsp, oWt0, ob0, y0p, B_, 1024, 480);
    gemm_p2<true><<<dim3(8, B_ / 128), 256, 0, stream>>>(y0p,    oWt1, ob1, y1p, B_, 1024, 1024);
    gemm_p2<true><<<dim3(4, B_ / 128), 256, 0, stream>>>(y1p,    oWt2, ob2, y2p, B_, 512, 1024);
    gemm_p2<true><<<dim3(2, B_ / 128), 256, 0, stream>>>(y2p,    oWt3, ob3, y3p, B_, 256, 512);

    final_dot<<<B_ / 4, 256, 0, stream>>>(y3p, oW4, ob4, out);
}

// Round 7
// 327.221 us; speedup vs baseline: 2.3446x; 1.0105x over previous
//
#include <hip/hip_runtime.h>

#define B_ 4096
#define F_ 26
#define L_ 10
#define V_ 100000
#define D_ 128

typedef __attribute__((ext_vector_type(8))) short short8;
typedef __attribute__((ext_vector_type(4))) float f32x4;

// fp32 -> packed (hi_bf16 << 16) | lo_bf16, both RNE. value ~= hi + lo.
__device__ inline unsigned pack_split(float f) {
    union { float f; unsigned u; } a; a.f = f;
    unsigned r = (a.u + 0x7FFFu + ((a.u >> 16) & 1u)) >> 16;
    union { unsigned u; float f; } hf; hf.u = r << 16;
    float rem = f - hf.f;
    union { float f; unsigned u; } b; b.f = rem;
    unsigned r2 = (b.u + 0x7FFFu + ((b.u >> 16) & 1u)) >> 16;
    return (r << 16) | (r2 & 0xFFFFu);
}
__device__ inline float unpack_f(unsigned u) {
    union { unsigned u; float f; } h; h.u = u & 0xFFFF0000u;
    union { unsigned u; float f; } l; l.u = u << 16;
    return h.f + l.f;
}

// ---- merged prep: 7 weight transposes + dense pad in ONE launch ----
__device__ void prep_tile(const float* __restrict__ W, unsigned* __restrict__ Wt,
                          int K, int N, int Kp, int local)
{
    __shared__ float tile[32][33];
    const int t = threadIdx.x;
    const int tx = t & 31, ty = t >> 5;
    const int nbt = N >> 5;
    const int nb = (local % nbt) << 5, kb = (local / nbt) << 5;
    #pragma unroll
    for (int i = 0; i < 4; ++i) {
        int k = kb + ty + i * 8;
        tile[ty + i * 8][tx] = (k < K) ? W[(size_t)k * N + nb + tx] : 0.f;
    }
    __syncthreads();
    #pragma unroll
    for (int i = 0; i < 4; ++i) {
        int nl = ty + i * 8;
        Wt[(size_t)(nb + nl) * Kp + kb + tx] = pack_split(tile[tx][nl]);
    }
}

__global__ __launch_bounds__(256) void prep_all(
    const float* dW0, const float* dW1, const float* dW2,
    const float* oW0, const float* oW1, const float* oW2, const float* oW3,
    unsigned* dWt0, unsigned* dWt1, unsigned* dWt2,
    unsigned* oWt0, unsigned* oWt1, unsigned* oWt2, unsigned* oWt3,
    const float* dense, unsigned* densep)
{
    const int bid = blockIdx.x;
    if      (bid < 16)   prep_tile(dW0, dWt0, 13,   512,  32,   bid);
    else if (bid < 144)  prep_tile(dW1, dWt1, 512,  256,  512,  bid - 16);
    else if (bid < 176)  prep_tile(dW2, dWt2, 256,  128,  256,  bid - 144);
    else if (bid < 656)  prep_tile(oW0, oWt0, 479,  1024, 480,  bid - 176);
    else if (bid < 1680) prep_tile(oW1, oWt1, 1024, 1024, 1024, bid - 656);
    else if (bid < 2192) prep_tile(oW2, oWt2, 1024, 512,  1024, bid - 1680);
    else if (bid < 2320) prep_tile(oW3, oWt3, 512,  256,  512,  bid - 2192);
    else {
        int g = (bid - 2320) * 256 + threadIdx.x;   // B*32 slots
        int b = g >> 5, k = g & 31;
        densep[g] = (k < 13) ? pack_split(dense[(size_t)b * 13 + k]) : 0u;
    }
}

// C = act(A @ W + bias), bf16x3 MFMA, DOUBLE-BUFFERED LDS (2-phase):
// STAGE(next) issued before COMPUTE(cur); one barrier per K-step, so the
// global_load_lds latency hides under perms+MFMA even at 1 block/CU.
template<bool RELU>
__global__ __launch_bounds__(256) void gemm_db(
    const unsigned* __restrict__ Ap, const unsigned* __restrict__ Wt,
    const float* __restrict__ bias, unsigned* __restrict__ Cp,
    int M, int N, int Kp)
{
    __shared__ __align__(16) unsigned Au[2][128 * 32];
    __shared__ __align__(16) unsigned Bu[2][128 * 32];

    const int t    = threadIdx.x;
    const int lane = t & 63;
    const int w    = t >> 6;
    const int wm   = w >> 1, wn = w & 1;
    const int m0   = blockIdx.y * 128, n0 = blockIdx.x * 128;

    f32x4 acc[4][4];
    const f32x4 zero = {0.f, 0.f, 0.f, 0.f};
    #pragma unroll
    for (int i = 0; i < 4; ++i)
        #pragma unroll
        for (int j = 0; j < 4; ++j) acc[i][j] = zero;

    const unsigned* Ab = Ap + (size_t)m0 * Kp;
    const unsigned* Bb = Wt + (size_t)n0 * Kp;

    const int g4 = lane >> 4;
    const int rr = lane & 15;

    auto STAGE = [&](int buf, int k0) {
        #pragma unroll
        for (int i = 0; i < 4; ++i) {
            int chunk = t + (i << 8);            // 0..1023 16B chunks
            int row = chunk >> 3, ch = chunk & 7;
            int sch = ch ^ (row & 7);            // source-side swizzle
            __builtin_amdgcn_global_load_lds(
                (const __attribute__((address_space(1))) unsigned*)(Ab + (size_t)row * Kp + k0 + (sch << 2)),
                &Au[buf][chunk << 2], 16, 0, 0);
            __builtin_amdgcn_global_load_lds(
                (const __attribute__((address_space(1))) unsigned*)(Bb + (size_t)row * Kp + k0 + (sch << 2)),
                &Bu[buf][chunk << 2], 16, 0, 0);
        }
    };

    auto COMPUTE = [&](int buf) {
        const unsigned* au = Au[buf];
        const unsigned* bu = Bu[buf];
        short8 bh[4], bl[4];
        #pragma unroll
        for (int tj = 0; tj < 4; ++tj) {
            int r = wn * 64 + tj * 16 + rr;
            int c0 = (2 * g4) ^ (r & 7), c1 = (2 * g4 + 1) ^ (r & 7);
            uint4 p = *reinterpret_cast<const uint4*>(&bu[r * 32 + (c0 << 2)]);
            uint4 q = *reinterpret_cast<const uint4*>(&bu[r * 32 + (c1 << 2)]);
            union { short8 s; uint4 u; } H, L;
            H.u.x = __builtin_amdgcn_perm(p.y, p.x, 0x07060302u);
            L.u.x = __builtin_amdgcn_perm(p.y, p.x, 0x05040100u);
            H.u.y = __builtin_amdgcn_perm(p.w, p.z, 0x07060302u);
            L.u.y = __builtin_amdgcn_perm(p.w, p.z, 0x05040100u);
            H.u.z = __builtin_amdgcn_perm(q.y, q.x, 0x07060302u);
            L.u.z = __builtin_amdgcn_perm(q.y, q.x, 0x05040100u);
            H.u.w = __builtin_amdgcn_perm(q.w, q.z, 0x07060302u);
            L.u.w = __builtin_amdgcn_perm(q.w, q.z, 0x05040100u);
            bh[tj] = H.s; bl[tj] = L.s;
        }
        #pragma unroll
        for (int ti = 0; ti < 4; ++ti) {
            int r = wm * 64 + ti * 16 + rr;
            int c0 = (2 * g4) ^ (r & 7), c1 = (2 * g4 + 1) ^ (r & 7);
            uint4 p = *reinterpret_cast<const uint4*>(&au[r * 32 + (c0 << 2)]);
            uint4 q = *reinterpret_cast<const uint4*>(&au[r * 32 + (c1 << 2)]);
            union { short8 s; uint4 u; } H, L;
            H.u.x = __builtin_amdgcn_perm(p.y, p.x, 0x07060302u);
            L.u.x = __builtin_amdgcn_perm(p.y, p.x, 0x05040100u);
            H.u.y = __builtin_amdgcn_perm(p.w, p.z, 0x07060302u);
            L.u.y = __builtin_amdgcn_perm(p.w, p.z, 0x05040100u);
            H.u.z = __builtin_amdgcn_perm(q.y, q.x, 0x07060302u);
            L.u.z = __builtin_amdgcn_perm(q.y, q.x, 0x05040100u);
            H.u.w = __builtin_amdgcn_perm(q.w, q.z, 0x07060302u);
            L.u.w = __builtin_amdgcn_perm(q.w, q.z, 0x05040100u);
            short8 ah = H.s, al = L.s;
            #pragma unroll
            for (int tj = 0; tj < 4; ++tj) {
                f32x4 c = acc[ti][tj];
                c = __builtin_amdgcn_mfma_f32_16x16x32_bf16(ah, bh[tj], c, 0, 0, 0);
                c = __builtin_amdgcn_mfma_f32_16x16x32_bf16(ah, bl[tj], c, 0, 0, 0);
                c = __builtin_amdgcn_mfma_f32_16x16x32_bf16(al, bh[tj], c, 0, 0, 0);
                acc[ti][tj] = c;
            }
        }
    };

    const int nt = Kp >> 5;
    STAGE(0, 0);
    __syncthreads();
    int cur = 0;
    for (int ts = 0; ts < nt - 1; ++ts) {
        STAGE(cur ^ 1, (ts + 1) << 5);   // prefetch next tile first
        COMPUTE(cur);                     // hide load latency under compute
        __syncthreads();                  // drains vmcnt + lgkmcnt
        cur ^= 1;
    }
    COMPUTE(cur);

    #pragma unroll
    for (int ti = 0; ti < 4; ++ti) {
        int row = m0 + wm * 64 + ti * 16 + ((lane >> 4) << 2);
        #pragma unroll
        for (int tj = 0; tj < 4; ++tj) {
            int col = n0 + wn * 64 + tj * 16 + (lane & 15);
            float bv = bias[col];
            #pragma unroll
            for (int r = 0; r < 4; ++r) {
                float v = acc[ti][tj][r] + bv;
                if (RELU) v = fmaxf(v, 0.f);
                Cp[(size_t)(row + r) * N + col] = pack_split(v);
            }
        }
    }
}

// One block per sample: float4 gather into LDS z, pairwise dots, packed feats.
__global__ __launch_bounds__(256) void gather_interact(
    const unsigned* __restrict__ x2p,      // [B,128] packed
    const int*      __restrict__ idx_words,
    const float*    __restrict__ tables,   // [26,100000,128] fp32
    unsigned*       __restrict__ featsp)   // [B,480] packed
{
    __shared__ __align__(16) float z[27][132];
    __shared__ int sidx[F_ * L_];
    __shared__ int sstride;
    const int b = blockIdx.x;
    const int t = threadIdx.x;

    if (t == 0) {
        int st = 2;  // int64: odd (high) words all zero
        for (int ww = 1; ww < 256; ww += 2)
            if (idx_words[ww] != 0) { st = 1; break; }
        sstride = st;
        featsp[(size_t)b * 480 + 479] = 0u;
    }
    __syncthreads();
    const int st = sstride;

    for (int s = t; s < F_ * L_; s += 256) {
        int v = idx_words[((size_t)b * F_ * L_ + s) * st];
        sidx[s] = v < 0 ? 0 : (v >= V_ ? V_ - 1 : v);
    }
    if (t < 128) {
        unsigned u = x2p[(size_t)b * 128 + t];
        z[0][t] = unpack_f(u);
        featsp[(size_t)b * 480 + t] = u;
    }
    __syncthreads();

    for (int s = t; s < F_ * 32; s += 256) {
        int f = s >> 5, d4 = s & 31;
        const float* tab = tables + (size_t)f * V_ * D_;
        float4 a4 = {0.f, 0.f, 0.f, 0.f};
        #pragma unroll
        for (int l = 0; l < L_; ++l) {
            int idx = sidx[f * L_ + l];
            float4 v = *reinterpret_cast<const float4*>(tab + (size_t)idx * D_ + (d4 << 2));
            a4.x += v.x; a4.y += v.y; a4.z += v.z; a4.w += v.w;
        }
        *reinterpret_cast<float4*>(&z[f + 1][d4 << 2]) = a4;
    }
    __syncthreads();

    for (int p = t; p < 351; p += 256) {
        int i = 0, rem = p;
        while (rem >= 26 - i) { rem -= 26 - i; ++i; }
        int j = i + 1 + rem;
        float4 s4 = {0.f, 0.f, 0.f, 0.f};
        for (int kk = 0; kk < 32; ++kk) {
            int k4 = (kk + t) & 31;
            float4 a = *reinterpret_cast<const float4*>(&z[i][k4 << 2]);
            float4 c = *reinterpret_cast<const float4*>(&z[j][k4 << 2]);
            s4.x += a.x * c.x; s4.y += a.y * c.y; s4.z += a.z * c.z; s4.w += a.w * c.w;
        }
        featsp[(size_t)b * 480 + 128 + p] = pack_split(s4.x + s4.y + s4.z + s4.w);
    }
}

// logits[b] = dot(unpack(y3p[b,:256]), w) + bias
__global__ __launch_bounds__(256) void final_dot(
    const unsigned* __restrict__ yp, const float* __restrict__ w,
    const float* __restrict__ bias, float* __restrict__ out)
{
    const int wave = threadIdx.x >> 6;
    const int lane = threadIdx.x & 63;
    const int b = blockIdx.x * 4 + wave;
    uint4 u = *reinterpret_cast<const uint4*>(yp + (size_t)b * 256 + lane * 4);
    float4 wv = *reinterpret_cast<const float4*>(&w[lane * 4]);
    float s = unpack_f(u.x) * wv.x + unpack_f(u.y) * wv.y +
              unpack_f(u.z) * wv.z + unpack_f(u.w) * wv.w;
    #pragma unroll
    for (int off = 32; off; off >>= 1) s += __shfl_xor(s, off);
    if (lane == 0) out[b] = s + bias[0];
}

extern "C" void kernel_launch(void* const* d_in, const int* in_sizes, int n_in,
                              void* d_out, int out_size, void* d_ws, size_t ws_size,
                              hipStream_t stream)
{
    const float* dense   = (const float*)d_in[0];
    const int*   indices = (const int*)  d_in[1];
    const float* tables  = (const float*)d_in[2];
    const float* dW0 = (const float*)d_in[3];  const float* db0 = (const float*)d_in[4];
    const float* dW1 = (const float*)d_in[5];  const float* db1 = (const float*)d_in[6];
    const float* dW2 = (const float*)d_in[7];  const float* db2 = (const float*)d_in[8];
    const float* oW0 = (const float*)d_in[9];  const float* ob0 = (const float*)d_in[10];
    const float* oW1 = (const float*)d_in[11]; const float* ob1 = (const float*)d_in[12];
    const float* oW2 = (const float*)d_in[13]; const float* ob2 = (const float*)d_in[14];
    const float* oW3 = (const float*)d_in[15]; const float* ob3 = (const float*)d_in[16];
    const float* oW4 = (const float*)d_in[17]; const float* ob4 = (const float*)d_in[18];
    float* out = (float*)d_out;

    unsigned* wsu = (unsigned*)d_ws;
    unsigned* dWt0 = wsu + 0;          // [512][32]
    unsigned* dWt1 = wsu + 16384;      // [256][512]
    unsigned* dWt2 = wsu + 147456;     // [128][256]
    unsigned* oWt0 = wsu + 180224;     // [1024][480]
    unsigned* oWt1 = wsu + 671744;     // [1024][1024]
    unsigned* oWt2 = wsu + 1720320;    // [512][1024]
    unsigned* oWt3 = wsu + 2244608;    // [256][512]
    unsigned* densep = wsu + 2375680;  // [4096][32]
    unsigned* x2p    = wsu + 2506752;  // [4096][128]
    unsigned* featsp = wsu + 3031040;  // [4096][480]
    unsigned* x0p    = wsu + 5000000;  // [4096][512]
    unsigned* x1p    = wsu + 7097152;  // [4096][256]
    unsigned* y0p    = wsu + 5000000;  // [4096][1024] (x0p/x1p dead)
    unsigned* y1p    = wsu + 9194304;  // [4096][1024]
    unsigned* y2p    = wsu + 2506752;  // [4096][512]  (x2p/featsp dead)
    unsigned* y3p    = wsu + 5000000;  // [4096][256]  (y0p dead)
    // high water 53.6 MB

    prep_all<<<2832, 256, 0, stream>>>(dW0, dW1, dW2, oW0, oW1, oW2, oW3,
                                       dWt0, dWt1, dWt2, oWt0, oWt1, oWt2, oWt3,
                                       dense, densep);

    gemm_db<true><<<dim3(4, B_ / 128), 256, 0, stream>>>(densep, dWt0, db0, x0p, B_, 512, 32);
    gemm_db<true><<<dim3(2, B_ / 128), 256, 0, stream>>>(x0p,    dWt1, db1, x1p, B_, 256, 512);
    gemm_db<true><<<dim3(1, B_ / 128), 256, 0, stream>>>(x1p,    dWt2, db2, x2p, B_, 128, 256);

    gather_interact<<<B_, 256, 0, stream>>>(x2p, indices, tables, featsp);

    gemm_db<true><<<dim3(8, B_ / 128), 256, 0, stream>>>(featsp, oWt0, ob0, y0p, B_, 1024, 480);
    gemm_db<true><<<dim3(8, B_ / 128), 256, 0, stream>>>(y0p,    oWt1, ob1, y1p, B_, 1024, 1024);
    gemm_db<true><<<dim3(4, B_ / 128), 256, 0, stream>>>(y1p,    oWt2, ob2, y2p, B_, 512, 1024);
    gemm_db<true><<<dim3(2, B_ / 128), 256, 0, stream>>>(y2p,    oWt3, ob3, y3p, B_, 256, 512);

    final_dot<<<B_ / 4, 256, 0, stream>>>(y3p, oW4, ob4, out);
}

// Round 8
// 294.611 us; speedup vs baseline: 2.6041x; 1.1107x over previous
//
#include <hip/hip_runtime.h>

#define B_ 4096
#define F_ 26
#define L_ 10
#define V_ 100000
#define D_ 128

typedef __attribute__((ext_vector_type(8))) short short8;
typedef __attribute__((ext_vector_type(4))) float f32x4;

// fp32 -> packed (hi_bf16 << 16) | lo_bf16, both RNE. value ~= hi + lo.
__device__ inline unsigned pack_split(float f) {
    union { float f; unsigned u; } a; a.f = f;
    unsigned r = (a.u + 0x7FFFu + ((a.u >> 16) & 1u)) >> 16;
    union { unsigned u; float f; } hf; hf.u = r << 16;
    float rem = f - hf.f;
    union { float f; unsigned u; } b; b.f = rem;
    unsigned r2 = (b.u + 0x7FFFu + ((b.u >> 16) & 1u)) >> 16;
    return (r << 16) | (r2 & 0xFFFFu);
}
__device__ inline float unpack_f(unsigned u) {
    union { unsigned u; float f; } h; h.u = u & 0xFFFF0000u;
    union { unsigned u; float f; } l; l.u = u << 16;
    return h.f + l.f;
}

// ---- merged prep: 7 weight transposes + dense pad in ONE launch ----
__device__ void prep_tile(const float* __restrict__ W, unsigned* __restrict__ Wt,
                          int K, int N, int Kp, int local)
{
    __shared__ float tile[32][33];
    const int t = threadIdx.x;
    const int tx = t & 31, ty = t >> 5;
    const int nbt = N >> 5;
    const int nb = (local % nbt) << 5, kb = (local / nbt) << 5;
    #pragma unroll
    for (int i = 0; i < 4; ++i) {
        int k = kb + ty + i * 8;
        tile[ty + i * 8][tx] = (k < K) ? W[(size_t)k * N + nb + tx] : 0.f;
    }
    __syncthreads();
    #pragma unroll
    for (int i = 0; i < 4; ++i) {
        int nl = ty + i * 8;
        Wt[(size_t)(nb + nl) * Kp + kb + tx] = pack_split(tile[tx][nl]);
    }
}

__global__ __launch_bounds__(256) void prep_all(
    const float* dW0, const float* dW1, const float* dW2,
    const float* oW0, const float* oW1, const float* oW2, const float* oW3,
    unsigned* dWt0, unsigned* dWt1, unsigned* dWt2,
    unsigned* oWt0, unsigned* oWt1, unsigned* oWt2, unsigned* oWt3,
    const float* dense, unsigned* densep)
{
    const int bid = blockIdx.x;
    if      (bid < 16)   prep_tile(dW0, dWt0, 13,   512,  32,   bid);
    else if (bid < 144)  prep_tile(dW1, dWt1, 512,  256,  512,  bid - 16);
    else if (bid < 176)  prep_tile(dW2, dWt2, 256,  128,  256,  bid - 144);
    else if (bid < 656)  prep_tile(oW0, oWt0, 479,  1024, 480,  bid - 176);
    else if (bid < 1680) prep_tile(oW1, oWt1, 1024, 1024, 1024, bid - 656);
    else if (bid < 2192) prep_tile(oW2, oWt2, 1024, 512,  1024, bid - 1680);
    else if (bid < 2320) prep_tile(oW3, oWt3, 512,  256,  512,  bid - 2192);
    else {
        int g = (bid - 2320) * 256 + threadIdx.x;   // B*32 slots
        int b = g >> 5, k = g & 31;
        densep[g] = (k < 13) ? pack_split(dense[(size_t)b * 13 + k]) : 0u;
    }
}

// C = act(A @ W + bias), bf16x3 MFMA, 8 waves (512t), wave-tile 64x32,
// double-buffered LDS; 2 waves/SIMD so MFMA overlaps perms/LDS of the
// sibling wave (m114 pipe overlap).
template<bool RELU>
__global__ __launch_bounds__(512) void gemm8(
    const unsigned* __restrict__ Ap, const unsigned* __restrict__ Wt,
    const float* __restrict__ bias, unsigned* __restrict__ Cp,
    int M, int N, int Kp)
{
    __shared__ __align__(16) unsigned Au[2][128 * 32];
    __shared__ __align__(16) unsigned Bu[2][128 * 32];

    const int t    = threadIdx.x;
    const int lane = t & 63;
    const int w    = t >> 6;
    const int wm   = w >> 2, wn = w & 3;
    const int m0   = blockIdx.y * 128, n0 = blockIdx.x * 128;

    f32x4 acc[4][2];
    const f32x4 zero = {0.f, 0.f, 0.f, 0.f};
    #pragma unroll
    for (int i = 0; i < 4; ++i)
        #pragma unroll
        for (int j = 0; j < 2; ++j) acc[i][j] = zero;

    const unsigned* Ab = Ap + (size_t)m0 * Kp;
    const unsigned* Bb = Wt + (size_t)n0 * Kp;

    const int g4 = lane >> 4;
    const int rr = lane & 15;

    auto STAGE = [&](int buf, int k0) {
        #pragma unroll
        for (int i = 0; i < 2; ++i) {
            int chunk = t + (i << 9);
            int row = chunk >> 3, ch = chunk & 7;
            int sch = ch ^ (row & 7);
            __builtin_amdgcn_global_load_lds(
                (const __attribute__((address_space(1))) unsigned*)(Ab + (size_t)row * Kp + k0 + (sch << 2)),
                &Au[buf][chunk << 2], 16, 0, 0);
        }
        #pragma unroll
        for (int i = 0; i < 2; ++i) {
            int chunk = t + (i << 9);
            int row = chunk >> 3, ch = chunk & 7;
            int sch = ch ^ (row & 7);
            __builtin_amdgcn_global_load_lds(
                (const __attribute__((address_space(1))) unsigned*)(Bb + (size_t)row * Kp + k0 + (sch << 2)),
                &Bu[buf][chunk << 2], 16, 0, 0);
        }
    };

    auto COMPUTE = [&](int buf) {
        const unsigned* au = Au[buf];
        const unsigned* bu = Bu[buf];
        short8 bh[2], bl[2];
        #pragma unroll
        for (int tj = 0; tj < 2; ++tj) {
            int r = wn * 32 + tj * 16 + rr;
            int c0 = (2 * g4) ^ (r & 7), c1 = (2 * g4 + 1) ^ (r & 7);
            uint4 p = *reinterpret_cast<const uint4*>(&bu[r * 32 + (c0 << 2)]);
            uint4 q = *reinterpret_cast<const uint4*>(&bu[r * 32 + (c1 << 2)]);
            union { short8 s; uint4 u; } H, L;
            H.u.x = __builtin_amdgcn_perm(p.y, p.x, 0x07060302u);
            L.u.x = __builtin_amdgcn_perm(p.y, p.x, 0x05040100u);
            H.u.y = __builtin_amdgcn_perm(p.w, p.z, 0x07060302u);
            L.u.y = __builtin_amdgcn_perm(p.w, p.z, 0x05040100u);
            H.u.z = __builtin_amdgcn_perm(q.y, q.x, 0x07060302u);
            L.u.z = __builtin_amdgcn_perm(q.y, q.x, 0x05040100u);
            H.u.w = __builtin_amdgcn_perm(q.w, q.z, 0x07060302u);
            L.u.w = __builtin_amdgcn_perm(q.w, q.z, 0x05040100u);
            bh[tj] = H.s; bl[tj] = L.s;
        }
        #pragma unroll
        for (int ti = 0; ti < 4; ++ti) {
            int r = wm * 64 + ti * 16 + rr;
            int c0 = (2 * g4) ^ (r & 7), c1 = (2 * g4 + 1) ^ (r & 7);
            uint4 p = *reinterpret_cast<const uint4*>(&au[r * 32 + (c0 << 2)]);
            uint4 q = *reinterpret_cast<const uint4*>(&au[r * 32 + (c1 << 2)]);
            union { short8 s; uint4 u; } H, L;
            H.u.x = __builtin_amdgcn_perm(p.y, p.x, 0x07060302u);
            L.u.x = __builtin_amdgcn_perm(p.y, p.x, 0x05040100u);
            H.u.y = __builtin_amdgcn_perm(p.w, p.z, 0x07060302u);
            L.u.y = __builtin_amdgcn_perm(p.w, p.z, 0x05040100u);
            H.u.z = __builtin_amdgcn_perm(q.y, q.x, 0x07060302u);
            L.u.z = __builtin_amdgcn_perm(q.y, q.x, 0x05040100u);
            H.u.w = __builtin_amdgcn_perm(q.w, q.z, 0x07060302u);
            L.u.w = __builtin_amdgcn_perm(q.w, q.z, 0x05040100u);
            short8 ah = H.s, al = L.s;
            #pragma unroll
            for (int tj = 0; tj < 2; ++tj) {
                f32x4 c = acc[ti][tj];
                c = __builtin_amdgcn_mfma_f32_16x16x32_bf16(ah, bh[tj], c, 0, 0, 0);
                c = __builtin_amdgcn_mfma_f32_16x16x32_bf16(ah, bl[tj], c, 0, 0, 0);
                c = __builtin_amdgcn_mfma_f32_16x16x32_bf16(al, bh[tj], c, 0, 0, 0);
                acc[ti][tj] = c;
            }
        }
    };

    const int nt = Kp >> 5;
    STAGE(0, 0);
    __syncthreads();
    int cur = 0;
    for (int ts = 0; ts < nt - 1; ++ts) {
        STAGE(cur ^ 1, (ts + 1) << 5);
        COMPUTE(cur);
        __syncthreads();
        cur ^= 1;
    }
    COMPUTE(cur);

    #pragma unroll
    for (int ti = 0; ti < 4; ++ti) {
        int row = m0 + wm * 64 + ti * 16 + (g4 << 2);
        #pragma unroll
        for (int tj = 0; tj < 2; ++tj) {
            int col = n0 + wn * 32 + tj * 16 + rr;
            float bv = bias[col];
            #pragma unroll
            for (int r = 0; r < 4; ++r) {
                float v = acc[ti][tj][r] + bv;
                if (RELU) v = fmaxf(v, 0.f);
                Cp[(size_t)(row + r) * N + col] = pack_split(v);
            }
        }
    }
}

// 4 samples per block, one wave per sample. Gather bags into LDS hi/lo
// bf16 planes (XOR chunk-swizzled), then 27x27 Gram matrix via bf16x3 MFMA
// (48 mfma/sample) instead of LDS dot-product loops.
__global__ __launch_bounds__(256) void gather_interact_mfma(
    const unsigned* __restrict__ x2p,      // [B,128] packed
    const int*      __restrict__ idx_words,
    const float*    __restrict__ tables,   // [26,100000,128] fp32
    unsigned*       __restrict__ featsp)   // [B,480] packed
{
    __shared__ unsigned zh[4][32][64];     // hi-plane: row r, dword d (2 cols)
    __shared__ unsigned zl[4][32][64];     // lo-plane
    __shared__ int sidx[4][F_ * L_];
    __shared__ int sstride;

    const int t    = threadIdx.x;
    const int w    = t >> 6;
    const int lane = t & 63;
    const int s    = blockIdx.x * 4 + w;   // sample

    if (t == 0) {
        int st = 2;  // int64: odd (high) words all zero
        for (int ww = 1; ww < 256; ww += 2)
            if (idx_words[ww] != 0) { st = 1; break; }
        sstride = st;
    }
    __syncthreads();
    const int st = sstride;

    // indices (clamped) + dense row + z row 0
    for (int q = lane; q < F_ * L_; q += 64) {
        int v = idx_words[((size_t)s * F_ * L_ + q) * st];
        sidx[w][q] = v < 0 ? 0 : (v >= V_ ? V_ - 1 : v);
    }
    uint2 xv = *reinterpret_cast<const uint2*>(x2p + (size_t)s * 128 + 2 * lane);
    *reinterpret_cast<uint2*>(featsp + (size_t)s * 480 + 2 * lane) = xv;
    if (lane == 0) featsp[(size_t)s * 480 + 479] = 0u;
    // row 0: swizzle is identity (r&7 == 0); dword lane holds cols 2l,2l+1
    zh[w][0][lane] = (xv.x >> 16) | (xv.y & 0xFFFF0000u);
    zl[w][0][lane] = (xv.x & 0xFFFFu) | (xv.y << 16);
    __syncthreads();

    // gather: one float2 per lane per bag row (512B = full row per wave instr)
    for (int f = 0; f < F_; ++f) {
        float2 a = {0.f, 0.f};
        const float* tab = tables + (size_t)f * V_ * D_;
        #pragma unroll
        for (int l = 0; l < L_; ++l) {
            int idx = sidx[w][f * L_ + l];
            float2 v = *reinterpret_cast<const float2*>(tab + (size_t)idx * D_ + 2 * lane);
            a.x += v.x; a.y += v.y;
        }
        unsigned px = pack_split(a.x), py = pack_split(a.y);
        int r  = f + 1;
        int dw = (((lane >> 2) ^ (r & 7)) << 2) + (lane & 3);  // chunk-swizzled dword
        zh[w][r][dw] = (px >> 16) | (py & 0xFFFF0000u);
        zl[w][r][dw] = (px & 0xFFFFu) | (py << 16);
    }
    __syncthreads();

    // interaction: 32x32 Gram over K=128 via bf16x3 MFMA (rows 27..31 unused)
    const int g4 = lane >> 4;
    const int rr = lane & 15;
    f32x4 acc[2][2];
    const f32x4 zero = {0.f, 0.f, 0.f, 0.f};
    acc[0][0] = zero; acc[0][1] = zero; acc[1][0] = zero; acc[1][1] = zero;

    #pragma unroll
    for (int ks = 0; ks < 4; ++ks) {
        short8 h[2], lo[2];
        #pragma unroll
        for (int mi = 0; mi < 2; ++mi) {
            int r = mi * 16 + rr;
            int c = (ks * 4 + g4) ^ (r & 7);
            h[mi]  = *reinterpret_cast<const short8*>(&zh[w][r][c << 2]);
            lo[mi] = *reinterpret_cast<const short8*>(&zl[w][r][c << 2]);
        }
        #pragma unroll
        for (int mi = 0; mi < 2; ++mi)
            #pragma unroll
            for (int nj = 0; nj < 2; ++nj) {
                f32x4 c = acc[mi][nj];
                c = __builtin_amdgcn_mfma_f32_16x16x32_bf16(h[mi],  h[nj],  c, 0, 0, 0);
                c = __builtin_amdgcn_mfma_f32_16x16x32_bf16(h[mi],  lo[nj], c, 0, 0, 0);
                c = __builtin_amdgcn_mfma_f32_16x16x32_bf16(lo[mi], h[nj],  c, 0, 0, 0);
                acc[mi][nj] = c;
            }
    }

    // extract upper triangle (i<j<=26), p = 26i - i(i-1)/2 + (j-i-1)
    #pragma unroll
    for (int mi = 0; mi < 2; ++mi) {
        #pragma unroll
        for (int nj = 0; nj < 2; ++nj) {
            #pragma unroll
            for (int r = 0; r < 4; ++r) {
                int i = mi * 16 + g4 * 4 + r;
                int j = nj * 16 + rr;
                if (i < j && j <= 26) {
                    int p = i * 26 - (i * (i - 1)) / 2 + (j - i - 1);
                    featsp[(size_t)s * 480 + 128 + p] = pack_split(acc[mi][nj][r]);
                }
            }
        }
    }
}

// logits[b] = dot(unpack(y3p[b,:256]), w) + bias
__global__ __launch_bounds__(256) void final_dot(
    const unsigned* __restrict__ yp, const float* __restrict__ w,
    const float* __restrict__ bias, float* __restrict__ out)
{
    const int wave = threadIdx.x >> 6;
    const int lane = threadIdx.x & 63;
    const int b = blockIdx.x * 4 + wave;
    uint4 u = *reinterpret_cast<const uint4*>(yp + (size_t)b * 256 + lane * 4);
    float4 wv = *reinterpret_cast<const float4*>(&w[lane * 4]);
    float s = unpack_f(u.x) * wv.x + unpack_f(u.y) * wv.y +
              unpack_f(u.z) * wv.z + unpack_f(u.w) * wv.w;
    #pragma unroll
    for (int off = 32; off; off >>= 1) s += __shfl_xor(s, off);
    if (lane == 0) out[b] = s + bias[0];
}

extern "C" void kernel_launch(void* const* d_in, const int* in_sizes, int n_in,
                              void* d_out, int out_size, void* d_ws, size_t ws_size,
                              hipStream_t stream)
{
    const float* dense   = (const float*)d_in[0];
    const int*   indices = (const int*)  d_in[1];
    const float* tables  = (const float*)d_in[2];
    const float* dW0 = (const float*)d_in[3];  const float* db0 = (const float*)d_in[4];
    const float* dW1 = (const float*)d_in[5];  const float* db1 = (const float*)d_in[6];
    const float* dW2 = (const float*)d_in[7];  const float* db2 = (const float*)d_in[8];
    const float* oW0 = (const float*)d_in[9];  const float* ob0 = (const float*)d_in[10];
    const float* oW1 = (const float*)d_in[11]; const float* ob1 = (const float*)d_in[12];
    const float* oW2 = (const float*)d_in[13]; const float* ob2 = (const float*)d_in[14];
    const float* oW3 = (const float*)d_in[15]; const float* ob3 = (const float*)d_in[16];
    const float* oW4 = (const float*)d_in[17]; const float* ob4 = (const float*)d_in[18];
    float* out = (float*)d_out;

    unsigned* wsu = (unsigned*)d_ws;
    unsigned* dWt0 = wsu + 0;          // [512][32]
    unsigned* dWt1 = wsu + 16384;      // [256][512]
    unsigned* dWt2 = wsu + 147456;     // [128][256]
    unsigned* oWt0 = wsu + 180224;     // [1024][480]
    unsigned* oWt1 = wsu + 671744;     // [1024][1024]
    unsigned* oWt2 = wsu + 1720320;    // [512][1024]
    unsigned* oWt3 = wsu + 2244608;    // [256][512]
    unsigned* densep = wsu + 2375680;  // [4096][32]
    unsigned* x2p    = wsu + 2506752;  // [4096][128]
    unsigned* featsp = wsu + 3031040;  // [4096][480]
    unsigned* x0p    = wsu + 5000000;  // [4096][512]
    unsigned* x1p    = wsu + 7097152;  // [4096][256]
    unsigned* y0p    = wsu + 5000000;  // [4096][1024] (x0p/x1p dead)
    unsigned* y1p    = wsu + 9194304;  // [4096][1024]
    unsigned* y2p    = wsu + 2506752;  // [4096][512]  (x2p/featsp dead)
    unsigned* y3p    = wsu + 5000000;  // [4096][256]  (y0p dead)
    // high water 53.6 MB

    prep_all<<<2832, 256, 0, stream>>>(dW0, dW1, dW2, oW0, oW1, oW2, oW3,
                                       dWt0, dWt1, dWt2, oWt0, oWt1, oWt2, oWt3,
                                       dense, densep);

    gemm8<true><<<dim3(4, B_ / 128), 512, 0, stream>>>(densep, dWt0, db0, x0p, B_, 512, 32);
    gemm8<true><<<dim3(2, B_ / 128), 512, 0, stream>>>(x0p,    dWt1, db1, x1p, B_, 256, 512);
    gemm8<true><<<dim3(1, B_ / 128), 512, 0, stream>>>(x1p,    dWt2, db2, x2p, B_, 128, 256);

    gather_interact_mfma<<<B_ / 4, 256, 0, stream>>>(x2p, indices, tables, featsp);

    gemm8<true><<<dim3(8, B_ / 128), 512, 0, stream>>>(featsp, oWt0, ob0, y0p, B_, 1024, 480);
    gemm8<true><<<dim3(8, B_ / 128), 512, 0, stream>>>(y0p,    oWt1, ob1, y1p, B_, 1024, 1024);
    gemm8<true><<<dim3(4, B_ / 128), 512, 0, stream>>>(y1p,    oWt2, ob2, y2p, B_, 512, 1024);
    gemm8<true><<<dim3(2, B_ / 128), 512, 0, stream>>>(y2p,    oWt3, ob3, y3p, B_, 256, 512);

    final_dot<<<B_ / 4, 256, 0, stream>>>(y3p, oW4, ob4, out);
}